// Round 7
// baseline (42.359 us; speedup 1.0000x reference)
//
#include <hip/hip_runtime.h>
#include <hip/hip_bf16.h>
#include <math.h>

// out[n] = top1(s) - top2(s),  s_c = 2 mu_c.x - ||mu_c||^2
//
// Kernel 1 (96 blocks x 64 thr): 64 KB bf16 B-fragment table + 32 fp32 sq
//   into d_ws (unchanged, proven).
// Kernel 2 (511 blocks x 512 thr, 98 rows/block, 1 block/CU):
//   X streamed as 512B-contiguous row-pair bursts into a wave-PRIVATE
//   2x4KB XOR-swizzled LDS double buffer; A-frags ds_read from LDS;
//   B-table staged linearly (proven). THIS ROUND: 3-buffer register
//   prefetch, distance TWO windows (~16KB outstanding per wave at all
//   times) so the CU's in-flight bytes never drop below the latency-BW
//   product -> no synchronized HBM-idle gaps between windows.
// A and B use the same k-slot mapping -> dot invariant to slot permutation.

#define KTOT  32
#define DDIM  1024
#define BLK2  512
#define RPB2  98     // rows per block -> grid 511

typedef __attribute__((ext_vector_type(8))) short short8v;
typedef __attribute__((ext_vector_type(4))) short short4v;
typedef __attribute__((ext_vector_type(4))) float f32x4;

__device__ __forceinline__ short f2bf(float x) {  // RNE; pairs into v_cvt_pk_bf16_f32
  __hip_bfloat16 h = __float2bfloat16(x);
  return __builtin_bit_cast(short, h);
}

// ---------------- kernel 1: build fragment table + sq in workspace ---------
__global__ __launch_bounds__(64)
void nkm_pre_kernel(const float* __restrict__ Cent, short* __restrict__ tbl) {
  const int b = blockIdx.x, t = threadIdx.x;
  if (b < 64) {
    const int i  = b * 64 + t;          // 0..4095
    const int l  = i & 63;
    const int st = i >> 6;
    const int col = ((st & 1) << 4) | (l & 15);
    const int d0  = ((st >> 1) << 5) + ((l >> 4) << 3);
    const float* cp = Cent + (size_t)col * DDIM + d0;
    f32x4 f0 = *(const f32x4*)cp;
    f32x4 f1 = *(const f32x4*)(cp + 4);
    short8v v;
    v[0] = f2bf(f0[0]); v[1] = f2bf(f0[1]); v[2] = f2bf(f0[2]); v[3] = f2bf(f0[3]);
    v[4] = f2bf(f1[0]); v[5] = f2bf(f1[1]); v[6] = f2bf(f1[2]); v[7] = f2bf(f1[3]);
    *(short8v*)(tbl + (size_t)i * 8) = v;
  } else {
    const int col = b - 64;             // 0..31
    const float* cp = Cent + (size_t)col * DDIM + t * 16;
    float a0 = 0.f, a1 = 0.f, a2 = 0.f, a3 = 0.f;
    #pragma unroll
    for (int j = 0; j < 4; ++j) {
      float4 v = *(const float4*)(cp + j * 4);
      a0 = fmaf(v.x, v.x, a0); a1 = fmaf(v.y, v.y, a1);
      a2 = fmaf(v.z, v.z, a2); a3 = fmaf(v.w, v.w, a3);
    }
    float s = (a0 + a1) + (a2 + a3);
    #pragma unroll
    for (int d = 1; d < 64; d <<= 1) s += __shfl_xor(s, d, 64);
    if (t == 0) ((float*)(tbl + 32768))[col] = s;
  }
}

// ---------------- kernel 2: stream X via private LDS, 2-window prefetch ----
__global__ __launch_bounds__(BLK2, 2)
void nkm_main_kernel(const float* __restrict__ X,
                     const short* __restrict__ tbl,
                     float* __restrict__ out, int N) {
  __shared__ short ldsAll[65536];   // 64 KB table + 8 waves x 8 KB X dbuf

  const int tid  = threadIdx.x;
  const int lane = tid & 63;
  const int wid  = tid >> 6;      // wave 0..7
  const int g    = lane >> 4;     // 16-lane group 0..3
  const int cc   = lane & 15;

  short* ldsB = ldsAll;                                  // table (linear, proven)
  char*  xbuf = (char*)&ldsAll[32768] + wid * 8192;      // private 2 x 4096 B

  const int blk_base = blockIdx.x * RPB2;
  int limit = blk_base + RPB2; if (limit > N) limit = N;
  const int rb = blk_base + wid * 16;

  // ---- loop-invariant row-pair pointers: instr j covers rows {2j, 2j+1},
  //      lane l -> row 2j+(l>>5), bytes (l&31)*16 within the 512B window run
  const float* pj[8];
  #pragma unroll
  for (int j = 0; j < 8; ++j) {
    int r = rb + 2 * j + (lane >> 5);
    if (r >= limit) r = limit - 1;       // clamped dup (cache hit), store off
    pj[j] = X + (size_t)r * DDIM + (lane & 31) * 4;
  }

  // ---- issue windows 0 AND 1 first (16 loads in flight during table stage)
  f32x4 r0[8], r1[8], r2[8];
  #pragma unroll
  for (int j = 0; j < 8; ++j) r0[j] = *(const f32x4*)(pj[j]);
  #pragma unroll
  for (int j = 0; j < 8; ++j) r1[j] = *(const f32x4*)(pj[j] + 128);

  // ---- stage 64 KB table: 8 rounds x 512 thr x 16 B, linear, conflict-free
  #pragma unroll
  for (int r = 0; r < 8; ++r) {
    const int i = r * 512 + tid;
    *(short8v*)&ldsB[(size_t)i * 8] = *(const short8v*)(tbl + (size_t)i * 8);
  }
  const float sq0 = ((const float*)(tbl + 32768))[cc];
  const float sq1 = ((const float*)(tbl + 32768))[cc + 16];
  __syncthreads();

  if (rb >= limit) return;        // idle waves exit after the barrier

  // staging/store address pieces
  const int wb0 = ((lane >> 5) << 8) + (lane & 31) * 8;  // row-half*256 + col*8

  // A-frag read offsets (per k-substep s'), swizzled: row=cc, slot=s'*4+g
  int raddr[4];
  #pragma unroll
  for (int sp = 0; sp < 4; ++sp) {
    int a = cc * 256 + (sp * 4 + g) * 16;
    raddr[sp] = a ^ (((a >> 8) & 0xF) << 4);
  }

  f32x4 acc0 = {0.f, 0.f, 0.f, 0.f};
  f32x4 acc1 = {0.f, 0.f, 0.f, 0.f};

  #pragma unroll
  for (int w = 0; w < 8; ++w) {               // 8 windows x 128 dims
    // select buffers statically (full unroll -> registers, rule #20)
    f32x4* curb = (w % 3 == 0) ? r0 : (w % 3 == 1) ? r1 : r2;
    f32x4* preb = ((w + 2) % 3 == 0) ? r0 : ((w + 2) % 3 == 1) ? r1 : r2;
    // prefetch window w+2 (keeps ~16KB/wave outstanding at all times)
    if (w < 6) {
      #pragma unroll
      for (int j = 0; j < 8; ++j) preb[j] = *(const f32x4*)(pj[j] + (w + 2) * 128);
    }
    // stage current window into private LDS (bf16, swizzled)
    char* bp = xbuf + (w & 1) * 4096;
    #pragma unroll
    for (int j = 0; j < 8; ++j) {
      int wb = wb0 + j * 512;
      wb ^= ((wb >> 8) & 0xF) << 4;
      f32x4 v = curb[j];
      short4v pk;
      pk[0] = f2bf(v[0]); pk[1] = f2bf(v[1]); pk[2] = f2bf(v[2]); pk[3] = f2bf(v[3]);
      *(short4v*)(bp + wb) = pk;
    }
    // 4 k-steps: A from private LDS, B from table, 2 MFMA chains
    #pragma unroll
    for (int sp = 0; sp < 4; ++sp) {
      const int s = w * 4 + sp;
      const short8v a  = *(const short8v*)(bp + raddr[sp]);
      const short8v b0 = *(const short8v*)&ldsB[(size_t)(((s << 1) | 0) * 64 + lane) * 8];
      const short8v b1 = *(const short8v*)&ldsB[(size_t)(((s << 1) | 1) * 64 + lane) * 8];
      acc0 = __builtin_amdgcn_mfma_f32_16x16x32_bf16(a, b0, acc0, 0, 0, 0);
      acc1 = __builtin_amdgcn_mfma_f32_16x16x32_bf16(a, b1, acc1, 0, 0, 0);
    }
  }

  // ---- epilogue: s = 2*dot - sq; top-2 across 16 lanes x 2 cols each
  const int rbase = rb + (g << 2);
  #pragma unroll
  for (int r = 0; r < 4; ++r) {
    float v0 = fmaf(2.f, acc0[r], -sq0);
    float v1 = fmaf(2.f, acc1[r], -sq1);
    float m1 = fmaxf(v0, v1);
    float m2 = fminf(v0, v1);
    #pragma unroll
    for (int d = 1; d <= 8; d <<= 1) {
      float om1 = __shfl_xor(m1, d, 64);
      float om2 = __shfl_xor(m2, d, 64);
      m2 = fmaxf(fmaxf(fminf(m1, om1), om2), m2);  // merged top-2
      m1 = fmaxf(m1, om1);
    }
    const int orow = rbase + r;
    if (cc == 0 && orow < limit) out[orow] = m1 - m2;
  }
}

extern "C" void kernel_launch(void* const* d_in, const int* in_sizes, int n_in,
                              void* d_out, int out_size, void* d_ws, size_t ws_size,
                              hipStream_t stream) {
  const float* X = (const float*)d_in[0];
  const float* C = (const float*)d_in[1];
  float* out = (float*)d_out;
  short* tbl = (short*)d_ws;                   // 64 KB frags + 128 B sq
  const int N = in_sizes[0] / DDIM;            // 50000
  const int blocks = (N + RPB2 - 1) / RPB2;    // 511
  hipLaunchKernelGGL(nkm_pre_kernel, dim3(96), dim3(64), 0, stream, C, tbl);
  hipLaunchKernelGGL(nkm_main_kernel, dim3(blocks), dim3(BLK2), 0, stream,
                     X, tbl, out, N);
}

// Round 8
// 42.333 us; speedup vs baseline: 1.0006x; 1.0006x over previous
//
#include <hip/hip_runtime.h>
#include <hip/hip_bf16.h>
#include <math.h>

// out[n] = top1(s) - top2(s),  s_c = 2 mu_c.x - ||mu_c||^2
//
// Kernel 1 (96 blocks x 64 thr): 64 KB bf16 B-fragment table + 32 fp32 sq
//   into d_ws (unchanged, proven).
// Kernel 2 (511 blocks x 512 thr, 98 rows/block, 1 block/CU):
//   X streamed as 512B-contiguous row-pair bursts into a wave-PRIVATE
//   2x4KB XOR-swizzled LDS double buffer; A-frags ds_read from LDS;
//   B-table staged linearly (proven). THIS ROUND: 3-buffer register
//   prefetch, distance TWO windows (~16KB outstanding per wave at all
//   times) so the CU's in-flight bytes never drop below the latency-BW
//   product -> no synchronized HBM-idle gaps between windows.
// A and B use the same k-slot mapping -> dot invariant to slot permutation.

#define KTOT  32
#define DDIM  1024
#define BLK2  512
#define RPB2  98     // rows per block -> grid 511

typedef __attribute__((ext_vector_type(8))) short short8v;
typedef __attribute__((ext_vector_type(4))) short short4v;
typedef __attribute__((ext_vector_type(4))) float f32x4;

__device__ __forceinline__ short f2bf(float x) {  // RNE; pairs into v_cvt_pk_bf16_f32
  __hip_bfloat16 h = __float2bfloat16(x);
  return __builtin_bit_cast(short, h);
}

// ---------------- kernel 1: build fragment table + sq in workspace ---------
__global__ __launch_bounds__(64)
void nkm_pre_kernel(const float* __restrict__ Cent, short* __restrict__ tbl) {
  const int b = blockIdx.x, t = threadIdx.x;
  if (b < 64) {
    const int i  = b * 64 + t;          // 0..4095
    const int l  = i & 63;
    const int st = i >> 6;
    const int col = ((st & 1) << 4) | (l & 15);
    const int d0  = ((st >> 1) << 5) + ((l >> 4) << 3);
    const float* cp = Cent + (size_t)col * DDIM + d0;
    f32x4 f0 = *(const f32x4*)cp;
    f32x4 f1 = *(const f32x4*)(cp + 4);
    short8v v;
    v[0] = f2bf(f0[0]); v[1] = f2bf(f0[1]); v[2] = f2bf(f0[2]); v[3] = f2bf(f0[3]);
    v[4] = f2bf(f1[0]); v[5] = f2bf(f1[1]); v[6] = f2bf(f1[2]); v[7] = f2bf(f1[3]);
    *(short8v*)(tbl + (size_t)i * 8) = v;
  } else {
    const int col = b - 64;             // 0..31
    const float* cp = Cent + (size_t)col * DDIM + t * 16;
    float a0 = 0.f, a1 = 0.f, a2 = 0.f, a3 = 0.f;
    #pragma unroll
    for (int j = 0; j < 4; ++j) {
      float4 v = *(const float4*)(cp + j * 4);
      a0 = fmaf(v.x, v.x, a0); a1 = fmaf(v.y, v.y, a1);
      a2 = fmaf(v.z, v.z, a2); a3 = fmaf(v.w, v.w, a3);
    }
    float s = (a0 + a1) + (a2 + a3);
    #pragma unroll
    for (int d = 1; d < 64; d <<= 1) s += __shfl_xor(s, d, 64);
    if (t == 0) ((float*)(tbl + 32768))[col] = s;
  }
}

// ---------------- kernel 2: stream X via private LDS, 2-window prefetch ----
__global__ __launch_bounds__(BLK2, 2)
void nkm_main_kernel(const float* __restrict__ X,
                     const short* __restrict__ tbl,
                     float* __restrict__ out, int N) {
  __shared__ short ldsAll[65536];   // 64 KB table + 8 waves x 8 KB X dbuf

  const int tid  = threadIdx.x;
  const int lane = tid & 63;
  const int wid  = tid >> 6;      // wave 0..7
  const int g    = lane >> 4;     // 16-lane group 0..3
  const int cc   = lane & 15;

  short* ldsB = ldsAll;                                  // table (linear, proven)
  char*  xbuf = (char*)&ldsAll[32768] + wid * 8192;      // private 2 x 4096 B

  const int blk_base = blockIdx.x * RPB2;
  int limit = blk_base + RPB2; if (limit > N) limit = N;
  const int rb = blk_base + wid * 16;

  // ---- loop-invariant row-pair pointers: instr j covers rows {2j, 2j+1},
  //      lane l -> row 2j+(l>>5), bytes (l&31)*16 within the 512B window run
  const float* pj[8];
  #pragma unroll
  for (int j = 0; j < 8; ++j) {
    int r = rb + 2 * j + (lane >> 5);
    if (r >= limit) r = limit - 1;       // clamped dup (cache hit), store off
    pj[j] = X + (size_t)r * DDIM + (lane & 31) * 4;
  }

  // ---- issue windows 0 AND 1 first (16 loads in flight during table stage)
  f32x4 r0[8], r1[8], r2[8];
  #pragma unroll
  for (int j = 0; j < 8; ++j) r0[j] = *(const f32x4*)(pj[j]);
  #pragma unroll
  for (int j = 0; j < 8; ++j) r1[j] = *(const f32x4*)(pj[j] + 128);

  // ---- stage 64 KB table: 8 rounds x 512 thr x 16 B, linear, conflict-free
  #pragma unroll
  for (int r = 0; r < 8; ++r) {
    const int i = r * 512 + tid;
    *(short8v*)&ldsB[(size_t)i * 8] = *(const short8v*)(tbl + (size_t)i * 8);
  }
  const float sq0 = ((const float*)(tbl + 32768))[cc];
  const float sq1 = ((const float*)(tbl + 32768))[cc + 16];
  __syncthreads();

  if (rb >= limit) return;        // idle waves exit after the barrier

  // staging/store address pieces
  const int wb0 = ((lane >> 5) << 8) + (lane & 31) * 8;  // row-half*256 + col*8

  // A-frag read offsets (per k-substep s'), swizzled: row=cc, slot=s'*4+g
  int raddr[4];
  #pragma unroll
  for (int sp = 0; sp < 4; ++sp) {
    int a = cc * 256 + (sp * 4 + g) * 16;
    raddr[sp] = a ^ (((a >> 8) & 0xF) << 4);
  }

  f32x4 acc0 = {0.f, 0.f, 0.f, 0.f};
  f32x4 acc1 = {0.f, 0.f, 0.f, 0.f};

  #pragma unroll
  for (int w = 0; w < 8; ++w) {               // 8 windows x 128 dims
    // select buffers statically (full unroll -> registers, rule #20)
    f32x4* curb = (w % 3 == 0) ? r0 : (w % 3 == 1) ? r1 : r2;
    f32x4* preb = ((w + 2) % 3 == 0) ? r0 : ((w + 2) % 3 == 1) ? r1 : r2;
    // prefetch window w+2 (keeps ~16KB/wave outstanding at all times)
    if (w < 6) {
      #pragma unroll
      for (int j = 0; j < 8; ++j) preb[j] = *(const f32x4*)(pj[j] + (w + 2) * 128);
    }
    // stage current window into private LDS (bf16, swizzled)
    char* bp = xbuf + (w & 1) * 4096;
    #pragma unroll
    for (int j = 0; j < 8; ++j) {
      int wb = wb0 + j * 512;
      wb ^= ((wb >> 8) & 0xF) << 4;
      f32x4 v = curb[j];
      short4v pk;
      pk[0] = f2bf(v[0]); pk[1] = f2bf(v[1]); pk[2] = f2bf(v[2]); pk[3] = f2bf(v[3]);
      *(short4v*)(bp + wb) = pk;
    }
    // 4 k-steps: A from private LDS, B from table, 2 MFMA chains
    #pragma unroll
    for (int sp = 0; sp < 4; ++sp) {
      const int s = w * 4 + sp;
      const short8v a  = *(const short8v*)(bp + raddr[sp]);
      const short8v b0 = *(const short8v*)&ldsB[(size_t)(((s << 1) | 0) * 64 + lane) * 8];
      const short8v b1 = *(const short8v*)&ldsB[(size_t)(((s << 1) | 1) * 64 + lane) * 8];
      acc0 = __builtin_amdgcn_mfma_f32_16x16x32_bf16(a, b0, acc0, 0, 0, 0);
      acc1 = __builtin_amdgcn_mfma_f32_16x16x32_bf16(a, b1, acc1, 0, 0, 0);
    }
  }

  // ---- epilogue: s = 2*dot - sq; top-2 across 16 lanes x 2 cols each
  const int rbase = rb + (g << 2);
  #pragma unroll
  for (int r = 0; r < 4; ++r) {
    float v0 = fmaf(2.f, acc0[r], -sq0);
    float v1 = fmaf(2.f, acc1[r], -sq1);
    float m1 = fmaxf(v0, v1);
    float m2 = fminf(v0, v1);
    #pragma unroll
    for (int d = 1; d <= 8; d <<= 1) {
      float om1 = __shfl_xor(m1, d, 64);
      float om2 = __shfl_xor(m2, d, 64);
      m2 = fmaxf(fmaxf(fminf(m1, om1), om2), m2);  // merged top-2
      m1 = fmaxf(m1, om1);
    }
    const int orow = rbase + r;
    if (cc == 0 && orow < limit) out[orow] = m1 - m2;
  }
}

extern "C" void kernel_launch(void* const* d_in, const int* in_sizes, int n_in,
                              void* d_out, int out_size, void* d_ws, size_t ws_size,
                              hipStream_t stream) {
  const float* X = (const float*)d_in[0];
  const float* C = (const float*)d_in[1];
  float* out = (float*)d_out;
  short* tbl = (short*)d_ws;                   // 64 KB frags + 128 B sq
  const int N = in_sizes[0] / DDIM;            // 50000
  const int blocks = (N + RPB2 - 1) / RPB2;    // 511
  hipLaunchKernelGGL(nkm_pre_kernel, dim3(96), dim3(64), 0, stream, C, tbl);
  hipLaunchKernelGGL(nkm_main_kernel, dim3(blocks), dim3(BLK2), 0, stream,
                     X, tbl, out, N);
}

// Round 9
// 42.079 us; speedup vs baseline: 1.0067x; 1.0060x over previous
//
#include <hip/hip_runtime.h>
#include <hip/hip_bf16.h>
#include <math.h>

// out[n] = top1(s) - top2(s),  s_c = 2 mu_c.x - ||mu_c||^2
//
// Kernel 1 (96 blocks x 64 thr): 64 KB bf16 B-fragment table + 32 fp32 sq
//   into d_ws (unchanged, proven).
// Kernel 2 (511 blocks x 512 thr, 98 rows/block, 1 block/CU):
//   X streamed as 512B-contiguous row-pair bursts into a wave-PRIVATE
//   2x4KB XOR-swizzled LDS double buffer; A-frags ds_read from LDS;
//   B-table staged linearly (proven). THIS ROUND: 3-buffer register
//   prefetch, distance TWO windows (~16KB outstanding per wave at all
//   times) so the CU's in-flight bytes never drop below the latency-BW
//   product -> no synchronized HBM-idle gaps between windows.
// A and B use the same k-slot mapping -> dot invariant to slot permutation.

#define KTOT  32
#define DDIM  1024
#define BLK2  512
#define RPB2  98     // rows per block -> grid 511

typedef __attribute__((ext_vector_type(8))) short short8v;
typedef __attribute__((ext_vector_type(4))) short short4v;
typedef __attribute__((ext_vector_type(4))) float f32x4;

__device__ __forceinline__ short f2bf(float x) {  // RNE; pairs into v_cvt_pk_bf16_f32
  __hip_bfloat16 h = __float2bfloat16(x);
  return __builtin_bit_cast(short, h);
}

// ---------------- kernel 1: build fragment table + sq in workspace ---------
__global__ __launch_bounds__(64)
void nkm_pre_kernel(const float* __restrict__ Cent, short* __restrict__ tbl) {
  const int b = blockIdx.x, t = threadIdx.x;
  if (b < 64) {
    const int i  = b * 64 + t;          // 0..4095
    const int l  = i & 63;
    const int st = i >> 6;
    const int col = ((st & 1) << 4) | (l & 15);
    const int d0  = ((st >> 1) << 5) + ((l >> 4) << 3);
    const float* cp = Cent + (size_t)col * DDIM + d0;
    f32x4 f0 = *(const f32x4*)cp;
    f32x4 f1 = *(const f32x4*)(cp + 4);
    short8v v;
    v[0] = f2bf(f0[0]); v[1] = f2bf(f0[1]); v[2] = f2bf(f0[2]); v[3] = f2bf(f0[3]);
    v[4] = f2bf(f1[0]); v[5] = f2bf(f1[1]); v[6] = f2bf(f1[2]); v[7] = f2bf(f1[3]);
    *(short8v*)(tbl + (size_t)i * 8) = v;
  } else {
    const int col = b - 64;             // 0..31
    const float* cp = Cent + (size_t)col * DDIM + t * 16;
    float a0 = 0.f, a1 = 0.f, a2 = 0.f, a3 = 0.f;
    #pragma unroll
    for (int j = 0; j < 4; ++j) {
      float4 v = *(const float4*)(cp + j * 4);
      a0 = fmaf(v.x, v.x, a0); a1 = fmaf(v.y, v.y, a1);
      a2 = fmaf(v.z, v.z, a2); a3 = fmaf(v.w, v.w, a3);
    }
    float s = (a0 + a1) + (a2 + a3);
    #pragma unroll
    for (int d = 1; d < 64; d <<= 1) s += __shfl_xor(s, d, 64);
    if (t == 0) ((float*)(tbl + 32768))[col] = s;
  }
}

// ---------------- kernel 2: stream X via private LDS, 2-window prefetch ----
__global__ __launch_bounds__(BLK2, 2)
void nkm_main_kernel(const float* __restrict__ X,
                     const short* __restrict__ tbl,
                     float* __restrict__ out, int N) {
  __shared__ short ldsAll[65536];   // 64 KB table + 8 waves x 8 KB X dbuf

  const int tid  = threadIdx.x;
  const int lane = tid & 63;
  const int wid  = tid >> 6;      // wave 0..7
  const int g    = lane >> 4;     // 16-lane group 0..3
  const int cc   = lane & 15;

  short* ldsB = ldsAll;                                  // table (linear, proven)
  char*  xbuf = (char*)&ldsAll[32768] + wid * 8192;      // private 2 x 4096 B

  const int blk_base = blockIdx.x * RPB2;
  int limit = blk_base + RPB2; if (limit > N) limit = N;
  const int rb = blk_base + wid * 16;

  // ---- loop-invariant row-pair pointers: instr j covers rows {2j, 2j+1},
  //      lane l -> row 2j+(l>>5), bytes (l&31)*16 within the 512B window run
  const float* pj[8];
  #pragma unroll
  for (int j = 0; j < 8; ++j) {
    int r = rb + 2 * j + (lane >> 5);
    if (r >= limit) r = limit - 1;       // clamped dup (cache hit), store off
    pj[j] = X + (size_t)r * DDIM + (lane & 31) * 4;
  }

  // ---- issue windows 0 AND 1 first (16 loads in flight during table stage)
  f32x4 r0[8], r1[8], r2[8];
  #pragma unroll
  for (int j = 0; j < 8; ++j) r0[j] = *(const f32x4*)(pj[j]);
  #pragma unroll
  for (int j = 0; j < 8; ++j) r1[j] = *(const f32x4*)(pj[j] + 128);

  // ---- stage 64 KB table: 8 rounds x 512 thr x 16 B, linear, conflict-free
  #pragma unroll
  for (int r = 0; r < 8; ++r) {
    const int i = r * 512 + tid;
    *(short8v*)&ldsB[(size_t)i * 8] = *(const short8v*)(tbl + (size_t)i * 8);
  }
  const float sq0 = ((const float*)(tbl + 32768))[cc];
  const float sq1 = ((const float*)(tbl + 32768))[cc + 16];
  __syncthreads();

  if (rb >= limit) return;        // idle waves exit after the barrier

  // staging/store address pieces
  const int wb0 = ((lane >> 5) << 8) + (lane & 31) * 8;  // row-half*256 + col*8

  // A-frag read offsets (per k-substep s'), swizzled: row=cc, slot=s'*4+g
  int raddr[4];
  #pragma unroll
  for (int sp = 0; sp < 4; ++sp) {
    int a = cc * 256 + (sp * 4 + g) * 16;
    raddr[sp] = a ^ (((a >> 8) & 0xF) << 4);
  }

  f32x4 acc0 = {0.f, 0.f, 0.f, 0.f};
  f32x4 acc1 = {0.f, 0.f, 0.f, 0.f};

  #pragma unroll
  for (int w = 0; w < 8; ++w) {               // 8 windows x 128 dims
    // select buffers statically (full unroll -> registers, rule #20)
    f32x4* curb = (w % 3 == 0) ? r0 : (w % 3 == 1) ? r1 : r2;
    f32x4* preb = ((w + 2) % 3 == 0) ? r0 : ((w + 2) % 3 == 1) ? r1 : r2;
    // prefetch window w+2 (keeps ~16KB/wave outstanding at all times)
    if (w < 6) {
      #pragma unroll
      for (int j = 0; j < 8; ++j) preb[j] = *(const f32x4*)(pj[j] + (w + 2) * 128);
    }
    // stage current window into private LDS (bf16, swizzled)
    char* bp = xbuf + (w & 1) * 4096;
    #pragma unroll
    for (int j = 0; j < 8; ++j) {
      int wb = wb0 + j * 512;
      wb ^= ((wb >> 8) & 0xF) << 4;
      f32x4 v = curb[j];
      short4v pk;
      pk[0] = f2bf(v[0]); pk[1] = f2bf(v[1]); pk[2] = f2bf(v[2]); pk[3] = f2bf(v[3]);
      *(short4v*)(bp + wb) = pk;
    }
    // 4 k-steps: A from private LDS, B from table, 2 MFMA chains
    #pragma unroll
    for (int sp = 0; sp < 4; ++sp) {
      const int s = w * 4 + sp;
      const short8v a  = *(const short8v*)(bp + raddr[sp]);
      const short8v b0 = *(const short8v*)&ldsB[(size_t)(((s << 1) | 0) * 64 + lane) * 8];
      const short8v b1 = *(const short8v*)&ldsB[(size_t)(((s << 1) | 1) * 64 + lane) * 8];
      acc0 = __builtin_amdgcn_mfma_f32_16x16x32_bf16(a, b0, acc0, 0, 0, 0);
      acc1 = __builtin_amdgcn_mfma_f32_16x16x32_bf16(a, b1, acc1, 0, 0, 0);
    }
  }

  // ---- epilogue: s = 2*dot - sq; top-2 across 16 lanes x 2 cols each
  const int rbase = rb + (g << 2);
  #pragma unroll
  for (int r = 0; r < 4; ++r) {
    float v0 = fmaf(2.f, acc0[r], -sq0);
    float v1 = fmaf(2.f, acc1[r], -sq1);
    float m1 = fmaxf(v0, v1);
    float m2 = fminf(v0, v1);
    #pragma unroll
    for (int d = 1; d <= 8; d <<= 1) {
      float om1 = __shfl_xor(m1, d, 64);
      float om2 = __shfl_xor(m2, d, 64);
      m2 = fmaxf(fmaxf(fminf(m1, om1), om2), m2);  // merged top-2
      m1 = fmaxf(m1, om1);
    }
    const int orow = rbase + r;
    if (cc == 0 && orow < limit) out[orow] = m1 - m2;
  }
}

extern "C" void kernel_launch(void* const* d_in, const int* in_sizes, int n_in,
                              void* d_out, int out_size, void* d_ws, size_t ws_size,
                              hipStream_t stream) {
  const float* X = (const float*)d_in[0];
  const float* C = (const float*)d_in[1];
  float* out = (float*)d_out;
  short* tbl = (short*)d_ws;                   // 64 KB frags + 128 B sq
  const int N = in_sizes[0] / DDIM;            // 50000
  const int blocks = (N + RPB2 - 1) / RPB2;    // 511
  hipLaunchKernelGGL(nkm_pre_kernel, dim3(96), dim3(64), 0, stream, C, tbl);
  hipLaunchKernelGGL(nkm_main_kernel, dim3(blocks), dim3(BLK2), 0, stream,
                     X, tbl, out, N);
}

// Round 10
// 41.134 us; speedup vs baseline: 1.0298x; 1.0230x over previous
//
#include <hip/hip_runtime.h>
#include <hip/hip_bf16.h>
#include <math.h>

// out[n] = top1(s) - top2(s),  s_c = 2 mu_c.x - ||mu_c||^2
//
// SINGLE fused kernel (511 blocks x 512 thr, 98 rows/block, 1 block/CU):
//  - issue X windows 0+1 FIRST (16 global_load_dwordx4 in flight)
//  - P1: gather-build 64 KB bf16 B-fragment table directly in LDS from
//    fp32 centroids (128 KB, L2/L3-hot; overlapped with X prefetch)
//  - P2: ||mu_c||^2 from the bf16 table (operand-consistent, fp32 accum)
//  - main loop: X streamed as 512B-contiguous row-pair bursts into a
//    wave-PRIVATE 2x4KB XOR-swizzled LDS double buffer; A-frags ds_read
//    from LDS; 3-buffer register prefetch (distance 2 windows); NO
//    nontemporal hints (round-4 confound removed); barrier-free main loop
//  - merged shfl_xor top-2 epilogue, one store per row
// A and B use the same k-slot mapping -> dot invariant to slot permutation.

#define KTOT  32
#define DDIM  1024
#define BLK   512
#define RPB   98     // rows per block -> grid 511

typedef __attribute__((ext_vector_type(8))) short short8v;
typedef __attribute__((ext_vector_type(4))) short short4v;
typedef __attribute__((ext_vector_type(4))) float f32x4;

__device__ __forceinline__ short f2bf(float x) {  // RNE; pairs into v_cvt_pk_bf16_f32
  __hip_bfloat16 h = __float2bfloat16(x);
  return __builtin_bit_cast(short, h);
}

__global__ __launch_bounds__(BLK, 2)
void nkm_fused_kernel(const float* __restrict__ X,
                      const float* __restrict__ Cent,
                      float* __restrict__ out, int N) {
  __shared__ short ldsAll[65536];   // 64 KB table + 8 waves x 8 KB X dbuf
  __shared__ float sqPart[BLK];     // 2 KB
  __shared__ float sqArr[KTOT];     // 128 B

  const int tid  = threadIdx.x;
  const int lane = tid & 63;
  const int wid  = tid >> 6;      // wave 0..7
  const int g    = lane >> 4;     // 16-lane group 0..3
  const int cc   = lane & 15;

  short* ldsB = ldsAll;                                  // table (linear, proven)
  char*  xbuf = (char*)&ldsAll[32768] + wid * 8192;      // private 2 x 4096 B

  const int blk_base = blockIdx.x * RPB;
  int limit = blk_base + RPB; if (limit > N) limit = N;
  const int rb = blk_base + wid * 16;

  // ---- loop-invariant row-pair pointers: instr j covers rows {2j, 2j+1},
  //      lane l -> row 2j+(l>>5), bytes (l&31)*16 within the 512B window run
  const float* pj[8];
  #pragma unroll
  for (int j = 0; j < 8; ++j) {
    int r = rb + 2 * j + (lane >> 5);
    if (r >= limit) r = limit - 1;       // clamped dup (cache hit), store off
    pj[j] = X + (size_t)r * DDIM + (lane & 31) * 4;
  }

  // ---- issue X windows 0 AND 1 first (16 loads to HBM, in flight during P1/P2)
  f32x4 r0[8], r1[8], r2[8];
  #pragma unroll
  for (int j = 0; j < 8; ++j) r0[j] = *(const f32x4*)(pj[j]);
  #pragma unroll
  for (int j = 0; j < 8; ++j) r1[j] = *(const f32x4*)(pj[j] + 128);

  // ---- P1: gather-build fragment table. item i: st=i>>6, l=i&63
  #pragma unroll
  for (int j = 0; j < 8; ++j) {
    const int i  = tid + j * BLK;        // 0..4095
    const int l  = i & 63;
    const int st = i >> 6;
    const int col = ((st & 1) << 4) | (l & 15);
    const int d0  = ((st >> 1) << 5) + ((l >> 4) << 3);
    const float* cp = Cent + (size_t)col * DDIM + d0;
    f32x4 f0 = *(const f32x4*)cp;
    f32x4 f1 = *(const f32x4*)(cp + 4);
    short8v v;
    v[0] = f2bf(f0[0]); v[1] = f2bf(f0[1]); v[2] = f2bf(f0[2]); v[3] = f2bf(f0[3]);
    v[4] = f2bf(f1[0]); v[5] = f2bf(f1[1]); v[6] = f2bf(f1[2]); v[7] = f2bf(f1[3]);
    *(short8v*)&ldsB[(size_t)i * 8] = v;
  }
  __syncthreads();

  // ---- P2: ||mu_c||^2 from bf16 frags (16 segs x 64 dims per col)
  {
    const int c = tid & 31, seg = tid >> 5;
    float s = 0.f;
    #pragma unroll
    for (int q = 0; q < 8; ++q) {
      const int d    = seg * 64 + q * 8;
      const int item = ((d >> 5) << 1) | (c >> 4);
      const int fl   = (c & 15) | (((d >> 3) & 3) << 4);
      short8v b = *(const short8v*)&ldsB[(size_t)(item * 64 + fl) * 8];
      #pragma unroll
      for (int e = 0; e < 8; ++e) {
        float bv = __uint_as_float(((unsigned)(unsigned short)b[e]) << 16);
        s = fmaf(bv, bv, s);
      }
    }
    sqPart[seg * 32 + c] = s;
  }
  __syncthreads();
  if (tid < KTOT) {
    float s = 0.f;
    #pragma unroll
    for (int j = 0; j < 16; ++j) s += sqPart[j * 32 + tid];
    sqArr[tid] = s;
  }
  __syncthreads();

  const float sq0 = sqArr[cc];
  const float sq1 = sqArr[cc + 16];

  if (rb >= limit) return;        // idle waves exit after all barriers

  // staging/store address pieces
  const int wb0 = ((lane >> 5) << 8) + (lane & 31) * 8;  // row-half*256 + col*8

  // A-frag read offsets (per k-substep s'), swizzled: row=cc, slot=s'*4+g
  int raddr[4];
  #pragma unroll
  for (int sp = 0; sp < 4; ++sp) {
    int a = cc * 256 + (sp * 4 + g) * 16;
    raddr[sp] = a ^ (((a >> 8) & 0xF) << 4);
  }

  f32x4 acc0 = {0.f, 0.f, 0.f, 0.f};
  f32x4 acc1 = {0.f, 0.f, 0.f, 0.f};

  #pragma unroll
  for (int w = 0; w < 8; ++w) {               // 8 windows x 128 dims
    // select buffers statically (full unroll -> registers, rule #20)
    f32x4* curb = (w % 3 == 0) ? r0 : (w % 3 == 1) ? r1 : r2;
    f32x4* preb = ((w + 2) % 3 == 0) ? r0 : ((w + 2) % 3 == 1) ? r1 : r2;
    // prefetch window w+2 (keeps ~16KB/wave outstanding at all times)
    if (w < 6) {
      #pragma unroll
      for (int j = 0; j < 8; ++j) preb[j] = *(const f32x4*)(pj[j] + (w + 2) * 128);
    }
    // stage current window into private LDS (bf16, swizzled)
    char* bp = xbuf + (w & 1) * 4096;
    #pragma unroll
    for (int j = 0; j < 8; ++j) {
      int wb = wb0 + j * 512;
      wb ^= ((wb >> 8) & 0xF) << 4;
      f32x4 v = curb[j];
      short4v pk;
      pk[0] = f2bf(v[0]); pk[1] = f2bf(v[1]); pk[2] = f2bf(v[2]); pk[3] = f2bf(v[3]);
      *(short4v*)(bp + wb) = pk;
    }
    // 4 k-steps: A from private LDS, B from table, 2 MFMA chains
    #pragma unroll
    for (int sp = 0; sp < 4; ++sp) {
      const int s = w * 4 + sp;
      const short8v a  = *(const short8v*)(bp + raddr[sp]);
      const short8v b0 = *(const short8v*)&ldsB[(size_t)(((s << 1) | 0) * 64 + lane) * 8];
      const short8v b1 = *(const short8v*)&ldsB[(size_t)(((s << 1) | 1) * 64 + lane) * 8];
      acc0 = __builtin_amdgcn_mfma_f32_16x16x32_bf16(a, b0, acc0, 0, 0, 0);
      acc1 = __builtin_amdgcn_mfma_f32_16x16x32_bf16(a, b1, acc1, 0, 0, 0);
    }
  }

  // ---- epilogue: s = 2*dot - sq; top-2 across 16 lanes x 2 cols each
  const int rbase = rb + (g << 2);
  #pragma unroll
  for (int r = 0; r < 4; ++r) {
    float v0 = fmaf(2.f, acc0[r], -sq0);
    float v1 = fmaf(2.f, acc1[r], -sq1);
    float m1 = fmaxf(v0, v1);
    float m2 = fminf(v0, v1);
    #pragma unroll
    for (int d = 1; d <= 8; d <<= 1) {
      float om1 = __shfl_xor(m1, d, 64);
      float om2 = __shfl_xor(m2, d, 64);
      m2 = fmaxf(fmaxf(fminf(m1, om1), om2), m2);  // merged top-2
      m1 = fmaxf(m1, om1);
    }
    const int orow = rbase + r;
    if (cc == 0 && orow < limit) out[orow] = m1 - m2;
  }
}

extern "C" void kernel_launch(void* const* d_in, const int* in_sizes, int n_in,
                              void* d_out, int out_size, void* d_ws, size_t ws_size,
                              hipStream_t stream) {
  const float* X = (const float*)d_in[0];
  const float* C = (const float*)d_in[1];
  float* out = (float*)d_out;
  const int N = in_sizes[0] / DDIM;            // 50000
  const int blocks = (N + RPB - 1) / RPB;      // 511
  hipLaunchKernelGGL(nkm_fused_kernel, dim3(blocks), dim3(BLK), 0, stream,
                     X, C, out, N);
}